// Round 3
// baseline (257.390 us; speedup 1.0000x reference)
//
#include <hip/hip_runtime.h>

// Sinkhorn, B=8 N=1024 C=64, T=2, eps=0.1, 20 iters, scale=1e-3.
// Only batch 7 contributes (reference returns losses[-1]).
// u = 1/(K v), v = 1/(K^T u), 20 rounds; loss = sum u_i K_ij v_j W_ij,
// W_ij = -0.1*log(K_ij).
//
// ROUND 3: same 3-kernel structure as round 2; ONLY the grid barrier changed.
//  - Round-2 barrier: 64 same-address fetch_adds -> serialized RMW chain at
//    the LLC (~2us of the 3us/round). Replaced with a FLAG-ARRAY barrier:
//    slot[bid] = generation (64 independent relaxed agent stores, parallel),
//    detect = wave 0 polls all 64 slots with one coalesced load per round,
//    divergent-exit loop == __all. No RMW anywhere.
//  - u/v exchange unchanged (proven): scalar agent-atomic stores -> LLC,
//    vectorized sc0 sc1 dwordx4 loads (forced L1/L2 miss, reads LLC).
//  - Numerics bitwise-identical to the passing round-2 kernel.

static constexpr int N = 1024;
static constexpr int C = 64;

// Workspace layout (floats).
static constexpr int WS_XS  = 0;          // softmax(y_s[7]/2) : 1024*64
static constexpr int WS_YS  = 65536;      // softmax(y_t[7]/2) : 1024*64
static constexpr int WS_K   = 131072;     // K   : 1024*1024
static constexpr int WS_KT  = 1179648;    // K^T : 1024*1024
static constexpr int WS_U   = 2228224;    // u : 1024
static constexpr int WS_V   = 2229248;    // v : 1024
static constexpr int WS_P   = 2230272;    // block partials : 256
static constexpr int WS_BAR = 2230592;    // 64 generation slots (u32)

typedef float f32x4 __attribute__((ext_vector_type(4)));

__device__ __forceinline__ float wsum(float v) {
    #pragma unroll
    for (int o = 32; o > 0; o >>= 1) v += __shfl_down(v, o, 64);
    return v;
}
__device__ __forceinline__ float wmax(float v) {
    #pragma unroll
    for (int o = 32; o > 0; o >>= 1) v = fmaxf(v, __shfl_down(v, o, 64));
    return v;
}

__device__ __forceinline__ float aload(float* p) {
    return __hip_atomic_load(p, __ATOMIC_RELAXED, __HIP_MEMORY_SCOPE_AGENT);
}
__device__ __forceinline__ void astore(float* p, float v) {
    __hip_atomic_store(p, v, __ATOMIC_RELAXED, __HIP_MEMORY_SCOPE_AGENT);
}
__device__ __forceinline__ unsigned aloadu(unsigned* p) {
    return __hip_atomic_load(p, __ATOMIC_RELAXED, __HIP_MEMORY_SCOPE_AGENT);
}
__device__ __forceinline__ void astoreu(unsigned* p, unsigned v) {
    __hip_atomic_store(p, v, __ATOMIC_RELAXED, __HIP_MEMORY_SCOPE_AGENT);
}

// Coherent wide loads: sc0 sc1 forces L1/L2 miss -> served by the LLC, where
// the agent-scope atomic stores of u/v land. s_waitcnt INSIDE the asm so the
// outputs are valid at asm end.
__device__ __forceinline__ void llc_load4(const float* p, f32x4& a0, f32x4& a1,
                                          f32x4& a2, f32x4& a3) {
    asm volatile(
        "global_load_dwordx4 %0, %4, off sc0 sc1\n\t"
        "global_load_dwordx4 %1, %4, off offset:1024 sc0 sc1\n\t"
        "global_load_dwordx4 %2, %4, off offset:2048 sc0 sc1\n\t"
        "global_load_dwordx4 %3, %4, off offset:3072 sc0 sc1\n\t"
        "s_waitcnt vmcnt(0)"
        : "=&v"(a0), "=&v"(a1), "=&v"(a2), "=&v"(a3)
        : "v"(p)
        : "memory");
}
__device__ __forceinline__ void llc_load1(const float* p, f32x4& a0) {
    asm volatile(
        "global_load_dwordx4 %0, %1, off sc0 sc1\n\t"
        "s_waitcnt vmcnt(0)"
        : "=&v"(a0) : "v"(p) : "memory");
}

// Flag-array grid barrier, 64 participants, fence-free.
// Arrival: one relaxed agent store to slot[bid] (parallel across blocks).
// Detect: lanes 0..63 of wave 0 poll slot[lane]; divergent-exit loop == __all.
// __syncthreads() before arrival drains vmcnt -> this block's u/v atomic
// stores are at the LLC before the flag becomes visible.
__device__ __forceinline__ void gridbar_f(unsigned* slots, unsigned& bar, int bid) {
    __syncthreads();
    ++bar;
    if (threadIdx.x == 0) astoreu(slots + bid, bar);
    if (threadIdx.x < 64) {
        while (aloadu(slots + threadIdx.x) < bar)
            __builtin_amdgcn_s_sleep(1);
    }
    asm volatile("" ::: "memory");
    __syncthreads();
}

// ---- 1: softmax over N axis (dim=1), batch 7. One block per column; 128 blocks.
__global__ void __launch_bounds__(256)
softmax_k(const float* __restrict__ ysrc, const float* __restrict__ ytrc,
          float* __restrict__ ws)
{
    __shared__ float sm[4];
    const int tid = threadIdx.x, bid = blockIdx.x;
    const int wid = tid >> 6, lane = tid & 63;
    const float* src = ((bid < C) ? ysrc : ytrc) + 7 * N * C;
    float* dst = ws + ((bid < C) ? WS_XS : WS_YS);
    const int c = bid & (C - 1);

    float vals[4];
    float m = -1e30f;
    #pragma unroll
    for (int q = 0; q < 4; ++q) {
        vals[q] = src[(q * 256 + tid) * C + c] * 0.5f;   // y / T, T = 2
        m = fmaxf(m, vals[q]);
    }
    m = wmax(m);
    if (lane == 0) sm[wid] = m;
    __syncthreads();
    m = fmaxf(fmaxf(sm[0], sm[1]), fmaxf(sm[2], sm[3]));
    float s = 0.f;
    #pragma unroll
    for (int q = 0; q < 4; ++q) { vals[q] = expf(vals[q] - m); s += vals[q]; }
    s = wsum(s);
    __syncthreads();                 // protect sm reuse
    if (lane == 0) sm[wid] = s;
    __syncthreads();
    s = sm[0] + sm[1] + sm[2] + sm[3];
    const float inv = 1.0f / s;
    #pragma unroll
    for (int q = 0; q < 4; ++q) dst[(q * 256 + tid) * C + c] = vals[q] * inv;
}

// ---- 2: K_ij = exp(-10 * sum_c |x_ic - y_jc|), plus K^T; 32x32 tiles, 4/block.
//        Blocks 0..3 init v = 1; block 0 zeroes the 64 barrier slots (agent
//        stores so the zeros are at the LLC, where loop_k polls).
__global__ void __launch_bounds__(256)
buildK_k(float* __restrict__ ws)
{
    __shared__ float smem[5184];   // sx 32*64 | sy 32*65 (+1 pad) | kt 32*33
    float* xs  = ws + WS_XS;
    float* ysm = ws + WS_YS;
    float* K   = ws + WS_K;
    float* KT  = ws + WS_KT;
    const int tid = threadIdx.x, bid = blockIdx.x;

    if (bid < 4) ws[WS_V + bid * 256 + tid] = 1.0f;   // v := 1
    if (bid == 0 && tid < 64) astoreu((unsigned*)(ws + WS_BAR) + tid, 0u);

    float* sx = smem;
    float* sy = smem + 2048;
    float* kt = smem + 4128;
    #pragma unroll 1
    for (int t = 0; t < 4; ++t) {
        const int tt = bid * 4 + t;
        const int ti = tt >> 5, tj = tt & 31;
        __syncthreads();
        for (int k = tid; k < 2048; k += 256) sx[k] = xs[ti * 2048 + k];
        for (int k = tid; k < 2048; k += 256)
            sy[(k >> 6) * 65 + (k & 63)] = ysm[tj * 2048 + k];
        __syncthreads();
        float kv[4];
        #pragma unroll
        for (int q = 0; q < 4; ++q) {
            const int idx = q * 256 + tid;
            const int il = idx >> 5, jl = idx & 31;
            float a = 0.f;
            #pragma unroll
            for (int c2 = 0; c2 < 64; ++c2)
                a += fabsf(sx[il * 64 + c2] - sy[jl * 65 + c2]);
            kv[q] = expf(-10.0f * a);                       // exp(-W/eps)
            K[(ti * 32 + il) * N + tj * 32 + jl] = kv[q];   // coalesced over jl
        }
        __syncthreads();
        #pragma unroll
        for (int q = 0; q < 4; ++q) {
            const int idx = q * 256 + tid;
            kt[(idx >> 5) * 33 + (idx & 31)] = kv[q];
        }
        __syncthreads();
        #pragma unroll
        for (int q = 0; q < 4; ++q) {
            const int idx = q * 256 + tid;
            const int jl = idx >> 5, il = idx & 31;
            KT[(tj * 32 + jl) * N + ti * 32 + il] = kt[il * 33 + jl];
        }
    }
}

// ---- 3: persistent loop kernel. 64 blocks x 256 threads; block owns rows
//         bid*16 .. bid*16+15 of both K and KT, resident in LDS.
__global__ void __launch_bounds__(256)
sinkhorn_loop_k(float* __restrict__ ws, float* __restrict__ out)
{
    __shared__ __align__(16) float rows[32 * 1024];  // K rows | KT rows (128KB)
    __shared__ __align__(16) float sv[1024];
    __shared__ float fsm[4];
    const int tid = threadIdx.x, bid = blockIdx.x;
    const int wid = tid >> 6, lane = tid & 63;
    unsigned bar = 0;
    unsigned* slots = (unsigned*)(ws + WS_BAR);

    // Preload this block's 16 K rows + 16 KT rows (rows are contiguous).
    {
        const f32x4* Ksrc  = (const f32x4*)(ws + WS_K  + bid * 16 * N);
        const f32x4* KTsrc = (const f32x4*)(ws + WS_KT + bid * 16 * N);
        f32x4* dK  = (f32x4*)rows;
        f32x4* dKT = (f32x4*)(rows + 16 * N);
        #pragma unroll 4
        for (int q = 0; q < 16; ++q) dK[tid + 256 * q]  = Ksrc[tid + 256 * q];
        #pragma unroll 4
        for (int q = 0; q < 16; ++q) dKT[tid + 256 * q] = KTsrc[tid + 256 * q];
    }
    __syncthreads();

    float* wsU = ws + WS_U;
    float* wsV = ws + WS_V;
    const float* myU = wsU + lane * 4;     // lane's float4 slices: +0,1,2,3 KB
    const float* myV = wsV + lane * 4;
    const int r0 = bid * 16 + wid * 4;     // wave's 4 rows
    const float* rK  = rows + (wid * 4) * N;
    const float* rKT = rows + 16 * N + (wid * 4) * N;
    float u_s[4];

    #pragma unroll 1
    for (int it = 0; it < 20; ++it) {
        // u = 1/(K v)
        f32x4 b0, b1, b2, b3;
        llc_load4(myV, b0, b1, b2, b3);
        #pragma unroll
        for (int s = 0; s < 4; ++s) {
            const f32x4* Kr = (const f32x4*)(rK + s * N);
            const f32x4 k0 = Kr[lane], k1 = Kr[lane + 64],
                        k2 = Kr[lane + 128], k3 = Kr[lane + 192];
            float acc = 0.f;
            acc += k0.x * b0.x + k0.y * b0.y + k0.z * b0.z + k0.w * b0.w;
            acc += k1.x * b1.x + k1.y * b1.y + k1.z * b1.z + k1.w * b1.w;
            acc += k2.x * b2.x + k2.y * b2.y + k2.z * b2.z + k2.w * b2.w;
            acc += k3.x * b3.x + k3.y * b3.y + k3.z * b3.z + k3.w * b3.w;
            acc = wsum(acc);
            if (lane == 0) { u_s[s] = 1.0f / acc; astore(wsU + r0 + s, u_s[s]); }
        }
        gridbar_f(slots, bar, bid);

        // v = 1/(K^T u)
        llc_load4(myU, b0, b1, b2, b3);
        #pragma unroll
        for (int s = 0; s < 4; ++s) {
            const f32x4* Kr = (const f32x4*)(rKT + s * N);
            const f32x4 k0 = Kr[lane], k1 = Kr[lane + 64],
                        k2 = Kr[lane + 128], k3 = Kr[lane + 192];
            float acc = 0.f;
            acc += k0.x * b0.x + k0.y * b0.y + k0.z * b0.z + k0.w * b0.w;
            acc += k1.x * b1.x + k1.y * b1.y + k1.z * b1.z + k1.w * b1.w;
            acc += k2.x * b2.x + k2.y * b2.y + k2.z * b2.z + k2.w * b2.w;
            acc += k3.x * b3.x + k3.y * b3.y + k3.z * b3.z + k3.w * b3.w;
            acc = wsum(acc);
            if (lane == 0) astore(wsV + r0 + s, 1.0f / acc);
        }
        gridbar_f(slots, bar, bid);
    }

    // Loss. Stage final v into LDS (one float4 per thread), then per wave the
    // 4 rows reproduce the old per-block partial: p = sum_s u_s * acc_s.
    {
        f32x4 vv;
        llc_load1(wsV + tid * 4, vv);
        *(f32x4*)(sv + tid * 4) = vv;
    }
    __syncthreads();
    {
        float p = 0.f;
        #pragma unroll
        for (int s = 0; s < 4; ++s) {
            const float* Kr = rK + s * N;      // LDS copy == K row r0+s bits
            float acc = 0.f;
            for (int j = lane; j < N; j += 64) {
                const float kk = Kr[j];
                acc += kk * sv[j] * logf(kk);
            }
            acc = wsum(acc);
            if (lane == 0) p += u_s[s] * acc;
        }
        if (lane == 0) astore(ws + WS_P + bid * 4 + wid, p);
    }
    gridbar_f(slots, bar, bid);

    // final: out = 1e-3 * sum_ij P*W = -1e-4 * sum(partials)
    if (bid == 0) {
        float acc = aload(ws + WS_P + tid);    // 256 partials, one per thread
        acc = wsum(acc);
        if (lane == 0) fsm[wid] = acc;
        __syncthreads();
        if (tid == 0)
            out[0] = -1e-4f * (fsm[0] + fsm[1] + fsm[2] + fsm[3]);
    }
}

extern "C" void kernel_launch(void* const* d_in, const int* in_sizes, int n_in,
                              void* d_out, int out_size, void* d_ws, size_t ws_size,
                              hipStream_t stream) {
    const float* y_s = (const float*)d_in[0];
    const float* y_t = (const float*)d_in[1];
    float* ws = (float*)d_ws;

    softmax_k<<<dim3(128), dim3(256), 0, stream>>>(y_s, y_t, ws);
    buildK_k<<<dim3(256), dim3(256), 0, stream>>>(ws);
    sinkhorn_loop_k<<<dim3(64), dim3(256), 0, stream>>>(ws, (float*)d_out);
}

// Round 4
// 245.222 us; speedup vs baseline: 1.0496x; 1.0496x over previous
//
#include <hip/hip_runtime.h>

// Sinkhorn, B=8 N=1024 C=64, T=2, eps=0.1, 20 iters, scale=1e-3.
// Only batch 7 contributes (reference returns losses[-1]).
// u = 1/(K v), v = 1/(K^T u), 20 rounds; loss = sum u_i K_ij v_j W_ij,
// W_ij = -0.1*log(K_ij).
//
// ROUND 4: single fused dispatch + two-stage counter-tree barrier.
//  - Barrier ranking measured so far: single-counter fetch_add 2.9us/rd <
//    flag-array 4.2 < 256-wide 7. This round: 8 group counters on separate
//    128B LLC lines (8 parallel 8-deep RMW chains) -> last-of-group bumps ONE
//    global counter -> everyone polls that single line (the round-2-proven
//    detection shape). All primitives are round-1/2-proven __hip_atomic ops.
//  - softmax/buildK fused in (256 blocks; blocks>=64 exit after buildK).
//    Build transitions use release/acquire "agent" fences (round-1-proven:
//    wbl2 flush + inv) around the barrier; loop barriers are fence-free
//    (u/v moves only through LLC-coherent atomics / sc0sc1 loads).
//  - Loop mechanics bitwise-identical to round 2: 64 blocks, 16 K-rows +
//    16 KT-rows per block in LDS, same float4 dot order, same wsum tree.

static constexpr int N = 1024;
static constexpr int C = 64;

// Workspace layout (floats).
static constexpr int WS_XS  = 0;          // softmax(y_s[7]/2) : 1024*64
static constexpr int WS_YS  = 65536;      // softmax(y_t[7]/2) : 1024*64
static constexpr int WS_K   = 131072;     // K   : 1024*1024
static constexpr int WS_KT  = 1179648;    // K^T : 1024*1024
static constexpr int WS_U   = 2228224;    // u : 1024
static constexpr int WS_V   = 2229248;    // v : 1024
static constexpr int WS_P   = 2230272;    // block partials : 256
static constexpr int WS_BAR = 2230592;    // barrier tree: 33 x 128B lines
// line 0 dword 0: global counter; line (1+g) dword 0: group-g counter.

typedef float f32x4 __attribute__((ext_vector_type(4)));

__device__ __forceinline__ float wsum(float v) {
    #pragma unroll
    for (int o = 32; o > 0; o >>= 1) v += __shfl_down(v, o, 64);
    return v;
}
__device__ __forceinline__ float wmax(float v) {
    #pragma unroll
    for (int o = 32; o > 0; o >>= 1) v = fmaxf(v, __shfl_down(v, o, 64));
    return v;
}

__device__ __forceinline__ float aload(float* p) {
    return __hip_atomic_load(p, __ATOMIC_RELAXED, __HIP_MEMORY_SCOPE_AGENT);
}
__device__ __forceinline__ void astore(float* p, float v) {
    __hip_atomic_store(p, v, __ATOMIC_RELAXED, __HIP_MEMORY_SCOPE_AGENT);
}

// Coherent wide loads: sc0 sc1 forces L1/L2 miss -> served by the LLC, where
// the agent-scope atomic stores of u/v land. waitcnt INSIDE the asm.
__device__ __forceinline__ void llc_load4(const float* p, f32x4& a0, f32x4& a1,
                                          f32x4& a2, f32x4& a3) {
    asm volatile(
        "global_load_dwordx4 %0, %4, off sc0 sc1\n\t"
        "global_load_dwordx4 %1, %4, off offset:1024 sc0 sc1\n\t"
        "global_load_dwordx4 %2, %4, off offset:2048 sc0 sc1\n\t"
        "global_load_dwordx4 %3, %4, off offset:3072 sc0 sc1\n\t"
        "s_waitcnt vmcnt(0)"
        : "=&v"(a0), "=&v"(a1), "=&v"(a2), "=&v"(a3)
        : "v"(p)
        : "memory");
}
__device__ __forceinline__ void llc_load1(const float* p, f32x4& a0) {
    asm volatile(
        "global_load_dwordx4 %0, %1, off sc0 sc1\n\t"
        "s_waitcnt vmcnt(0)"
        : "=&v"(a0) : "v"(p) : "memory");
}

// Two-stage counter-tree barrier. Monotonic counters; mixed populations are
// handled by register-tracked cumulative targets:
//   gtarget = cumulative arrivals expected on MY group's line (+8 / barrier)
//   gtotal  = cumulative group-completions on the global line (+ngroups)
// thread0 arrives on group line (8-deep RMW chain, parallel across groups);
// the group's last arriver bumps the global counter; everyone polls the
// single global line (proven-cheap detection shape).
template <bool FENCE>
__device__ __forceinline__ void treebar(unsigned* base, int grp,
                                        unsigned gtarget, unsigned gtotal) {
    __syncthreads();
    if (threadIdx.x == 0) {
        if (FENCE) __builtin_amdgcn_fence(__ATOMIC_RELEASE, "agent");
        unsigned* gln = base + 32 + grp * 32;          // own 128B line
        unsigned my = __hip_atomic_fetch_add(gln, 1u, __ATOMIC_RELAXED,
                                             __HIP_MEMORY_SCOPE_AGENT) + 1u;
        if (my == gtarget)
            __hip_atomic_fetch_add(base, 1u, __ATOMIC_RELAXED,
                                   __HIP_MEMORY_SCOPE_AGENT);
        while (__hip_atomic_load(base, __ATOMIC_RELAXED,
                                 __HIP_MEMORY_SCOPE_AGENT) < gtotal)
            __builtin_amdgcn_s_sleep(1);
        if (FENCE) __builtin_amdgcn_fence(__ATOMIC_ACQUIRE, "agent");
    }
    asm volatile("" ::: "memory");
    __syncthreads();
}

__global__ void __launch_bounds__(256)
sinkhorn_fused(const float* __restrict__ ysrc, const float* __restrict__ ytrc,
               float* __restrict__ ws, float* __restrict__ out)
{
    __shared__ __align__(16) float rows[32 * 1024];  // loop: K|KT rows (128KB)
    __shared__ __align__(16) float sv[1024];
    __shared__ float fsm[4];
    const int tid = threadIdx.x, bid = blockIdx.x;
    const int wid = tid >> 6, lane = tid & 63;
    const int grp = bid >> 3;                 // 32 groups of 8 (loop: 0..7)
    unsigned* base = (unsigned*)(ws + WS_BAR);
    unsigned gtarget = 0, gtotal = 0;

    // ---- Phase A: softmax over N axis (dim=1), batch 7. Blocks 0..127.
    if (bid < 2 * C) {
        const float* src = ((bid < C) ? ysrc : ytrc) + 7 * N * C;
        float* dst = ws + ((bid < C) ? WS_XS : WS_YS);
        const int c = bid & (C - 1);
        float vals[4];
        float m = -1e30f;
        #pragma unroll
        for (int q = 0; q < 4; ++q) {
            vals[q] = src[(q * 256 + tid) * C + c] * 0.5f;   // y / T, T = 2
            m = fmaxf(m, vals[q]);
        }
        m = wmax(m);
        if (lane == 0) fsm[wid] = m;
        __syncthreads();
        m = fmaxf(fmaxf(fsm[0], fsm[1]), fmaxf(fsm[2], fsm[3]));
        float s = 0.f;
        #pragma unroll
        for (int q = 0; q < 4; ++q) { vals[q] = expf(vals[q] - m); s += vals[q]; }
        s = wsum(s);
        __syncthreads();                 // protect fsm reuse
        if (lane == 0) fsm[wid] = s;
        __syncthreads();
        s = fsm[0] + fsm[1] + fsm[2] + fsm[3];
        const float inv = 1.0f / s;
        #pragma unroll
        for (int q = 0; q < 4; ++q) dst[(q * 256 + tid) * C + c] = vals[q] * inv;
    }
    gtarget += 8; gtotal += 32;
    treebar<true>(base, grp, gtarget, gtotal);    // publish XS/YS

    // ---- Phase B: K_ij = exp(-10 * sum_c |x_ic - y_jc|) and K^T. v := 1.
    {
        float* xs  = ws + WS_XS;
        float* ysm = ws + WS_YS;
        float* K   = ws + WS_K;
        float* KT  = ws + WS_KT;
        if (bid < 4) astore(ws + WS_V + bid * 256 + tid, 1.0f);  // LLC-direct

        float* sx = rows;
        float* sy = rows + 2048;
        float* kt = rows + 4128;
        #pragma unroll 1
        for (int t = 0; t < 4; ++t) {
            const int tt = bid * 4 + t;
            const int ti = tt >> 5, tj = tt & 31;
            __syncthreads();
            for (int k = tid; k < 2048; k += 256) sx[k] = xs[ti * 2048 + k];
            for (int k = tid; k < 2048; k += 256)
                sy[(k >> 6) * 65 + (k & 63)] = ysm[tj * 2048 + k];
            __syncthreads();
            float kv[4];
            #pragma unroll
            for (int q = 0; q < 4; ++q) {
                const int idx = q * 256 + tid;
                const int il = idx >> 5, jl = idx & 31;
                float a = 0.f;
                #pragma unroll
                for (int c2 = 0; c2 < 64; ++c2)
                    a += fabsf(sx[il * 64 + c2] - sy[jl * 65 + c2]);
                kv[q] = expf(-10.0f * a);                       // exp(-W/eps)
                K[(ti * 32 + il) * N + tj * 32 + jl] = kv[q];
            }
            __syncthreads();
            #pragma unroll
            for (int q = 0; q < 4; ++q) {
                const int idx = q * 256 + tid;
                kt[(idx >> 5) * 33 + (idx & 31)] = kv[q];
            }
            __syncthreads();
            #pragma unroll
            for (int q = 0; q < 4; ++q) {
                const int idx = q * 256 + tid;
                const int jl = idx >> 5, il = idx & 31;
                KT[(tj * 32 + jl) * N + ti * 32 + il] = kt[il * 33 + jl];
            }
        }
    }
    gtarget += 8; gtotal += 32;
    treebar<true>(base, grp, gtarget, gtotal);    // publish K/KT (wbl2+inv)

    if (bid >= 64) return;                        // build-only blocks retire

    // ---- Phase C: preload this block's 16 K rows + 16 KT rows into LDS.
    // Normal loads are safe: B2's acquire fence invalidated L1/L2.
    {
        const f32x4* Ksrc  = (const f32x4*)(ws + WS_K  + bid * 16 * N);
        const f32x4* KTsrc = (const f32x4*)(ws + WS_KT + bid * 16 * N);
        f32x4* dK  = (f32x4*)rows;
        f32x4* dKT = (f32x4*)(rows + 16 * N);
        #pragma unroll 4
        for (int q = 0; q < 16; ++q) dK[tid + 256 * q]  = Ksrc[tid + 256 * q];
        #pragma unroll 4
        for (int q = 0; q < 16; ++q) dKT[tid + 256 * q] = KTsrc[tid + 256 * q];
    }
    __syncthreads();

    float* wsU = ws + WS_U;
    float* wsV = ws + WS_V;
    const float* myU = wsU + lane * 4;     // lane's float4 slices: +0,1,2,3 KB
    const float* myV = wsV + lane * 4;
    const int r0 = bid * 16 + wid * 4;     // wave's 4 rows
    const float* rK  = rows + (wid * 4) * N;
    const float* rKT = rows + 16 * N + (wid * 4) * N;
    float u_s[4];

    // ---- Phase D: 20 x { u = 1/(K v) ; v = 1/(K^T u) }, fence-free barriers.
    #pragma unroll 1
    for (int it = 0; it < 20; ++it) {
        // u = 1/(K v)
        f32x4 b0, b1, b2, b3;
        llc_load4(myV, b0, b1, b2, b3);
        #pragma unroll
        for (int s = 0; s < 4; ++s) {
            const f32x4* Kr = (const f32x4*)(rK + s * N);
            const f32x4 k0 = Kr[lane], k1 = Kr[lane + 64],
                        k2 = Kr[lane + 128], k3 = Kr[lane + 192];
            float acc = 0.f;
            acc += k0.x * b0.x + k0.y * b0.y + k0.z * b0.z + k0.w * b0.w;
            acc += k1.x * b1.x + k1.y * b1.y + k1.z * b1.z + k1.w * b1.w;
            acc += k2.x * b2.x + k2.y * b2.y + k2.z * b2.z + k2.w * b2.w;
            acc += k3.x * b3.x + k3.y * b3.y + k3.z * b3.z + k3.w * b3.w;
            acc = wsum(acc);
            if (lane == 0) { u_s[s] = 1.0f / acc; astore(wsU + r0 + s, u_s[s]); }
        }
        gtarget += 8; gtotal += 8;
        treebar<false>(base, grp, gtarget, gtotal);

        // v = 1/(K^T u)
        llc_load4(myU, b0, b1, b2, b3);
        #pragma unroll
        for (int s = 0; s < 4; ++s) {
            const f32x4* Kr = (const f32x4*)(rKT + s * N);
            const f32x4 k0 = Kr[lane], k1 = Kr[lane + 64],
                        k2 = Kr[lane + 128], k3 = Kr[lane + 192];
            float acc = 0.f;
            acc += k0.x * b0.x + k0.y * b0.y + k0.z * b0.z + k0.w * b0.w;
            acc += k1.x * b1.x + k1.y * b1.y + k1.z * b1.z + k1.w * b1.w;
            acc += k2.x * b2.x + k2.y * b2.y + k2.z * b2.z + k2.w * b2.w;
            acc += k3.x * b3.x + k3.y * b3.y + k3.z * b3.z + k3.w * b3.w;
            acc = wsum(acc);
            if (lane == 0) astore(wsV + r0 + s, 1.0f / acc);
        }
        gtarget += 8; gtotal += 8;
        treebar<false>(base, grp, gtarget, gtotal);
    }

    // ---- Phase E: loss partials (same bits as round 2).
    {
        f32x4 vv;
        llc_load1(wsV + tid * 4, vv);
        *(f32x4*)(sv + tid * 4) = vv;
    }
    __syncthreads();
    {
        float p = 0.f;
        #pragma unroll
        for (int s = 0; s < 4; ++s) {
            const float* Kr = rK + s * N;      // LDS copy == K row r0+s bits
            float acc = 0.f;
            for (int j = lane; j < N; j += 64) {
                const float kk = Kr[j];
                acc += kk * sv[j] * logf(kk);
            }
            acc = wsum(acc);
            if (lane == 0) p += u_s[s] * acc;
        }
        if (lane == 0) astore(ws + WS_P + bid * 4 + wid, p);
    }
    gtarget += 8; gtotal += 8;
    treebar<false>(base, grp, gtarget, gtotal);

    // ---- final: out = 1e-3 * sum_ij P*W = -1e-4 * sum(partials)
    if (bid == 0) {
        float acc = aload(ws + WS_P + tid);    // 256 partials, one per thread
        acc = wsum(acc);
        if (lane == 0) fsm[wid] = acc;
        __syncthreads();
        if (tid == 0)
            out[0] = -1e-4f * (fsm[0] + fsm[1] + fsm[2] + fsm[3]);
    }
}

extern "C" void kernel_launch(void* const* d_in, const int* in_sizes, int n_in,
                              void* d_out, int out_size, void* d_ws, size_t ws_size,
                              hipStream_t stream) {
    const float* y_s = (const float*)d_in[0];
    const float* y_t = (const float*)d_in[1];
    float* ws = (float*)d_ws;

    // Zero the 33-line barrier tree (poisoned workspace); graph-capturable.
    hipMemsetAsync((char*)d_ws + (size_t)WS_BAR * sizeof(float), 0,
                   33 * 128, stream);
    sinkhorn_fused<<<dim3(256), dim3(256), 0, stream>>>(y_s, y_t, ws,
                                                        (float*)d_out);
}

// Round 6
// 200.239 us; speedup vs baseline: 1.2854x; 1.2246x over previous
//
#include <hip/hip_runtime.h>

// Sinkhorn, B=8 N=1024 C=64, T=2, eps=0.1, 20 iters, scale=1e-3.
// Only batch 7 contributes (reference returns losses[-1]).
// u = 1/(K v), v = 1/(K^T u), 20 rounds; loss = sum u_i K_ij v_j W_ij,
// W_ij = -0.1*log(K_ij).
//
// ROUND 6: LL-style data-embedded synchronization (NCCL/RCCL LL pattern).
//  Barrier ranking measured: flat-64 2.9us/rd < flag 4.2 < tree 4.6 < flat-256
//  7; hierarchical XCD attempt hung (unproven primitives). All barrier designs
//  pay serial LLC round trips ON TOP of the u/v data round trip. This round
//  deletes the barrier: each u/v element is published as an 8-byte unit
//  {float, generation tag} via one global_store_dwordx2 sc0 sc1 (8B aligned
//  stores are atomic). Readers poll-read the units directly and accept only
//  tag==expected. Serial chain per round = store-visible + poll-read. No RMW,
//  no counters, no fences. u/v double-buffer gives generation separation;
//  exact-tag match + in-launch memset of the LL regions kills poison/ABA.
//  softmax/buildK and every FLOP/reduction order: bit-identical to the
//  passing round-2 kernel.

static constexpr int N = 1024;
static constexpr int C = 64;

// Workspace layout (floats).
static constexpr int WS_XS  = 0;          // softmax(y_s[7]/2) : 1024*64
static constexpr int WS_YS  = 65536;      // softmax(y_t[7]/2) : 1024*64
static constexpr int WS_K   = 131072;     // K   : 1024*1024
static constexpr int WS_KT  = 1179648;    // K^T : 1024*1024
static constexpr int WS_ULL = 2228224;    // u LL units: 1024 x {f32,tag} = 2048 f
static constexpr int WS_VLL = 2230272;    // v LL units: 2048 f
static constexpr int WS_PLL = 2232320;    // partial LL units: 256 x {f32,tag}

typedef float    f32x4 __attribute__((ext_vector_type(4)));
typedef unsigned u32x4 __attribute__((ext_vector_type(4)));
typedef unsigned u32x2 __attribute__((ext_vector_type(2)));

__device__ __forceinline__ float wsum(float v) {
    #pragma unroll
    for (int o = 32; o > 0; o >>= 1) v += __shfl_down(v, o, 64);
    return v;
}
__device__ __forceinline__ float wmax(float v) {
    #pragma unroll
    for (int o = 32; o > 0; o >>= 1) v = fmaxf(v, __shfl_down(v, o, 64));
    return v;
}

// Publish one LL unit {val, g}: single 8B store, sc0 sc1 -> lands at the LLC.
__device__ __forceinline__ void ll_write(float* unit, float val, unsigned g) {
    u32x2 d;
    d.x = __float_as_uint(val);
    d.y = g;
    asm volatile("global_store_dwordx2 %0, %1, off sc0 sc1"
                 :: "v"(unit), "v"(d) : "memory");
}

// Poll-read 4 LL units (thread t covers units t*4..t*4+3) into sv[t*4..].
// Two 16B sc0 sc1 loads per try; accept when all 4 embedded tags == g.
// 8B-atomic stores guarantee each {val,tag} pair is internally consistent.
__device__ __forceinline__ void ll_read4(const float* buf, unsigned g,
                                         float* sv, int t) {
    const float* p = buf + t * 8;          // 4 units * 2 floats
    u32x4 a, b;
    for (;;) {
        asm volatile(
            "global_load_dwordx4 %0, %2, off sc0 sc1\n\t"
            "global_load_dwordx4 %1, %2, off offset:16 sc0 sc1\n\t"
            "s_waitcnt vmcnt(0)"
            : "=&v"(a), "=&v"(b) : "v"(p) : "memory");
        if (a.y == g && a.w == g && b.y == g && b.w == g) break;
        __builtin_amdgcn_s_sleep(1);
    }
    const int u0 = t * 4;
    sv[u0 + 0] = __uint_as_float(a.x);
    sv[u0 + 1] = __uint_as_float(a.z);
    sv[u0 + 2] = __uint_as_float(b.x);
    sv[u0 + 3] = __uint_as_float(b.z);
}

// ---- 1: softmax over N axis (dim=1), batch 7. One block per column; 128 blocks.
__global__ void __launch_bounds__(256)
softmax_k(const float* __restrict__ ysrc, const float* __restrict__ ytrc,
          float* __restrict__ ws)
{
    __shared__ float sm[4];
    const int tid = threadIdx.x, bid = blockIdx.x;
    const int wid = tid >> 6, lane = tid & 63;
    const float* src = ((bid < C) ? ysrc : ytrc) + 7 * N * C;
    float* dst = ws + ((bid < C) ? WS_XS : WS_YS);
    const int c = bid & (C - 1);

    float vals[4];
    float m = -1e30f;
    #pragma unroll
    for (int q = 0; q < 4; ++q) {
        vals[q] = src[(q * 256 + tid) * C + c] * 0.5f;   // y / T, T = 2
        m = fmaxf(m, vals[q]);
    }
    m = wmax(m);
    if (lane == 0) sm[wid] = m;
    __syncthreads();
    m = fmaxf(fmaxf(sm[0], sm[1]), fmaxf(sm[2], sm[3]));
    float s = 0.f;
    #pragma unroll
    for (int q = 0; q < 4; ++q) { vals[q] = expf(vals[q] - m); s += vals[q]; }
    s = wsum(s);
    __syncthreads();                 // protect sm reuse
    if (lane == 0) sm[wid] = s;
    __syncthreads();
    s = sm[0] + sm[1] + sm[2] + sm[3];
    const float inv = 1.0f / s;
    #pragma unroll
    for (int q = 0; q < 4; ++q) dst[(q * 256 + tid) * C + c] = vals[q] * inv;
}

// ---- 2: K_ij = exp(-10 * sum_c |x_ic - y_jc|), plus K^T; 32x32 tiles, 4/block.
//        Blocks 0..3 write the initial v LL units' VALUE slots (1.0f); the tag
//        slots are already 0 from the in-launch memset, and expected tag for
//        the first u-step is 0. Kernel-boundary coherence (round-2-proven)
//        makes these plain stores visible to the loop kernel's sc0sc1 reads.
__global__ void __launch_bounds__(256)
buildK_k(float* __restrict__ ws)
{
    __shared__ float smem[5184];   // sx 32*64 | sy 32*65 (+1 pad) | kt 32*33
    float* xs  = ws + WS_XS;
    float* ysm = ws + WS_YS;
    float* K   = ws + WS_K;
    float* KT  = ws + WS_KT;
    const int tid = threadIdx.x, bid = blockIdx.x;

    if (bid < 4) ws[WS_VLL + (bid * 256 + tid) * 2] = 1.0f;   // v := 1 (LL value)

    float* sx = smem;
    float* sy = smem + 2048;
    float* kt = smem + 4128;
    #pragma unroll 1
    for (int t = 0; t < 4; ++t) {
        const int tt = bid * 4 + t;
        const int ti = tt >> 5, tj = tt & 31;
        __syncthreads();
        for (int k = tid; k < 2048; k += 256) sx[k] = xs[ti * 2048 + k];
        for (int k = tid; k < 2048; k += 256)
            sy[(k >> 6) * 65 + (k & 63)] = ysm[tj * 2048 + k];
        __syncthreads();
        float kv[4];
        #pragma unroll
        for (int q = 0; q < 4; ++q) {
            const int idx = q * 256 + tid;
            const int il = idx >> 5, jl = idx & 31;
            float a = 0.f;
            #pragma unroll
            for (int c2 = 0; c2 < 64; ++c2)
                a += fabsf(sx[il * 64 + c2] - sy[jl * 65 + c2]);
            kv[q] = expf(-10.0f * a);                       // exp(-W/eps)
            K[(ti * 32 + il) * N + tj * 32 + jl] = kv[q];   // coalesced over jl
        }
        __syncthreads();
        #pragma unroll
        for (int q = 0; q < 4; ++q) {
            const int idx = q * 256 + tid;
            kt[(idx >> 5) * 33 + (idx & 31)] = kv[q];
        }
        __syncthreads();
        #pragma unroll
        for (int q = 0; q < 4; ++q) {
            const int idx = q * 256 + tid;
            const int jl = idx >> 5, il = idx & 31;
            KT[(tj * 32 + jl) * N + ti * 32 + il] = kt[il * 33 + jl];
        }
    }
}

// ---- 3: persistent loop kernel. 64 blocks x 256 threads; block owns rows
//         bid*16 .. bid*16+15 of both K and KT, resident in LDS. All cross-
//         block exchange via LL units; no barriers of any kind.
__global__ void __launch_bounds__(256)
sinkhorn_loop_k(float* __restrict__ ws, float* __restrict__ out)
{
    __shared__ __align__(16) float rows[32 * 1024];  // K rows | KT rows (128KB)
    __shared__ __align__(16) float sv[1024];
    __shared__ float stage[16];
    __shared__ float fsm[4];
    const int tid = threadIdx.x, bid = blockIdx.x;
    const int wid = tid >> 6, lane = tid & 63;

    // Preload this block's 16 K rows + 16 KT rows (rows are contiguous).
    {
        const f32x4* Ksrc  = (const f32x4*)(ws + WS_K  + bid * 16 * N);
        const f32x4* KTsrc = (const f32x4*)(ws + WS_KT + bid * 16 * N);
        f32x4* dK  = (f32x4*)rows;
        f32x4* dKT = (f32x4*)(rows + 16 * N);
        #pragma unroll 4
        for (int q = 0; q < 16; ++q) dK[tid + 256 * q]  = Ksrc[tid + 256 * q];
        #pragma unroll 4
        for (int q = 0; q < 16; ++q) dKT[tid + 256 * q] = KTsrc[tid + 256 * q];
    }
    __syncthreads();

    float* uLL = ws + WS_ULL;
    float* vLL = ws + WS_VLL;
    float* pLL = ws + WS_PLL;
    const float* rK  = rows + (wid * 4) * N;
    const float* rKT = rows + 16 * N + (wid * 4) * N;
    float u_s[4];
    unsigned g = 0;          // generation: u-steps publish odd, v-steps even

    #pragma unroll 1
    for (int it = 0; it < 20; ++it) {
        // ---- u = 1/(K v): consume v@g, publish u@g+1.
        ll_read4(vLL, g, sv, tid);
        __syncthreads();
        #pragma unroll
        for (int s = 0; s < 4; ++s) {
            const f32x4* Kr = (const f32x4*)(rK + s * N);
            const f32x4 k0 = Kr[lane], k1 = Kr[lane + 64],
                        k2 = Kr[lane + 128], k3 = Kr[lane + 192];
            const f32x4 b0 = *(const f32x4*)&sv[(lane) * 4];
            const f32x4 b1 = *(const f32x4*)&sv[(lane + 64) * 4];
            const f32x4 b2 = *(const f32x4*)&sv[(lane + 128) * 4];
            const f32x4 b3 = *(const f32x4*)&sv[(lane + 192) * 4];
            float acc = 0.f;
            acc += k0.x * b0.x + k0.y * b0.y + k0.z * b0.z + k0.w * b0.w;
            acc += k1.x * b1.x + k1.y * b1.y + k1.z * b1.z + k1.w * b1.w;
            acc += k2.x * b2.x + k2.y * b2.y + k2.z * b2.z + k2.w * b2.w;
            acc += k3.x * b3.x + k3.y * b3.y + k3.z * b3.z + k3.w * b3.w;
            acc = wsum(acc);
            if (lane == 0) { u_s[s] = 1.0f / acc; stage[wid * 4 + s] = u_s[s]; }
        }
        __syncthreads();     // all dots done (sv free), stage complete
        ++g;
        if (tid < 16) ll_write(uLL + (bid * 16 + tid) * 2, stage[tid], g);

        // ---- v = 1/(K^T u): consume u@g, publish v@g+1.
        ll_read4(uLL, g, sv, tid);
        __syncthreads();
        #pragma unroll
        for (int s = 0; s < 4; ++s) {
            const f32x4* Kr = (const f32x4*)(rKT + s * N);
            const f32x4 k0 = Kr[lane], k1 = Kr[lane + 64],
                        k2 = Kr[lane + 128], k3 = Kr[lane + 192];
            const f32x4 b0 = *(const f32x4*)&sv[(lane) * 4];
            const f32x4 b1 = *(const f32x4*)&sv[(lane + 64) * 4];
            const f32x4 b2 = *(const f32x4*)&sv[(lane + 128) * 4];
            const f32x4 b3 = *(const f32x4*)&sv[(lane + 192) * 4];
            float acc = 0.f;
            acc += k0.x * b0.x + k0.y * b0.y + k0.z * b0.z + k0.w * b0.w;
            acc += k1.x * b1.x + k1.y * b1.y + k1.z * b1.z + k1.w * b1.w;
            acc += k2.x * b2.x + k2.y * b2.y + k2.z * b2.z + k2.w * b2.w;
            acc += k3.x * b3.x + k3.y * b3.y + k3.z * b3.z + k3.w * b3.w;
            acc = wsum(acc);
            if (lane == 0) stage[wid * 4 + s] = 1.0f / acc;
        }
        __syncthreads();
        ++g;
        if (tid < 16) ll_write(vLL + (bid * 16 + tid) * 2, stage[tid], g);
    }

    // ---- Loss: consume final v@40; partials as LL units tagged 41.
    ll_read4(vLL, g, sv, tid);           // g == 40
    __syncthreads();
    {
        float p = 0.f;
        #pragma unroll
        for (int s = 0; s < 4; ++s) {
            const float* Kr = rK + s * N;      // LDS copy == K row bits
            float acc = 0.f;
            for (int j = lane; j < N; j += 64) {
                const float kk = Kr[j];
                acc += kk * sv[j] * logf(kk);
            }
            acc = wsum(acc);
            if (lane == 0) p += u_s[s] * acc;
        }
        if (lane == 0) ll_write(pLL + (bid * 4 + wid) * 2, p, 41u);
    }

    // ---- final: block 0 polls the 256 partial units, reduces, writes out.
    if (bid == 0) {
        const float* pp = pLL + tid * 2;
        u32x2 c;
        for (;;) {
            asm volatile("global_load_dwordx2 %0, %1, off sc0 sc1\n\t"
                         "s_waitcnt vmcnt(0)"
                         : "=&v"(c) : "v"(pp) : "memory");
            if (c.y == 41u) break;
            __builtin_amdgcn_s_sleep(1);
        }
        float acc = __uint_as_float(c.x);
        acc = wsum(acc);
        if (lane == 0) fsm[wid] = acc;
        __syncthreads();
        if (tid == 0)
            out[0] = -1e-4f * (fsm[0] + fsm[1] + fsm[2] + fsm[3]);  // 1e-3*(-0.1)
    }
}

extern "C" void kernel_launch(void* const* d_in, const int* in_sizes, int n_in,
                              void* d_out, int out_size, void* d_ws, size_t ws_size,
                              hipStream_t stream) {
    const float* y_s = (const float*)d_in[0];
    const float* y_t = (const float*)d_in[1];
    float* ws = (float*)d_ws;

    // Zero all LL regions (tags live in poisoned workspace); graph-capturable,
    // replayed every launch. 2048+2048+512 floats = 18432 B.
    hipMemsetAsync((char*)d_ws + (size_t)WS_ULL * sizeof(float), 0,
                   (size_t)(2048 + 2048 + 512) * sizeof(float), stream);
    softmax_k<<<dim3(128), dim3(256), 0, stream>>>(y_s, y_t, ws);
    buildK_k<<<dim3(256), dim3(256), 0, stream>>>(ws);
    sinkhorn_loop_k<<<dim3(64), dim3(256), 0, stream>>>(ws, (float*)d_out);
}